// Round 5
// baseline (11301.433 us; speedup 1.0000x reference)
//
#include <hip/hip_runtime.h>
#include <hip/hip_cooperative_groups.h>
#include <math.h>

namespace cg = cooperative_groups;

// ESBN: encoder (conv x3 + linear) + 64-step LSTM/memory scan. fp32.
// R5: E1/E2 encoder split (occupancy), persistent cooperative scan kernel.

__device__ __forceinline__ float sigm(float x) { return 1.0f / (1.0f + expf(-x)); }

// ---------------------------------------------------------------------------
// prep: transposed weights in ws.
//   WT [580][2048] (rows 0..64 w_ih^T, 65..576 w_hh^T, 577..579 zero),
//   bsum[2048], w1T[48][32], w2T[512][64], w3T[1024][64], ewT[256][64]
// ---------------------------------------------------------------------------
#define PREP_N (1187840 + 2048 + 1536 + 32768 + 65536 + 16384)
__global__ __launch_bounds__(256) void prep_kernel(
    const float* __restrict__ w_ih, const float* __restrict__ w_hh,
    const float* __restrict__ b_ih, const float* __restrict__ b_hh,
    const float* __restrict__ w1, const float* __restrict__ w2,
    const float* __restrict__ w3, const float* __restrict__ ew,
    float* __restrict__ WT, float* __restrict__ bsum,
    float* __restrict__ w1T, float* __restrict__ w2T,
    float* __restrict__ w3T, float* __restrict__ ewT)
{
  int i = blockIdx.x * 256 + threadIdx.x;
  if (i < 1187840) {
    const int r = i >> 11, c = i & 2047;
    float v;
    if (r < 65)       v = w_ih[(size_t)c * 65 + r];
    else if (r < 577) v = w_hh[(size_t)c * 512 + (r - 65)];
    else              v = 0.0f;
    WT[i] = v; return;
  }
  i -= 1187840;
  if (i < 2048) { bsum[i] = b_ih[i] + b_hh[i]; return; }
  i -= 2048;
  if (i < 1536) { const int r = i >> 5, oc = i & 31; w1T[i] = w1[oc * 48 + r]; return; }
  i -= 1536;
  if (i < 32768) { const int r = i >> 6, oc = i & 63; w2T[i] = w2[oc * 512 + r]; return; }
  i -= 32768;
  if (i < 65536) { const int r = i >> 6, oc = i & 63; w3T[i] = w3[oc * 1024 + r]; return; }
  i -= 65536;
  if (i < 16384) { const int k = i >> 6, d = i & 63; ewT[i] = ew[d * 256 + k]; return; }
}

// ---------------------------------------------------------------------------
// E1: conv1 only (3->32, k4 s2, out 15x15, ReLU), one block per sample.
// LDS = image only (12 KB) -> ~10 blocks/CU. Output to global c1g[bid][32][240]
// (row stride 16, col 15 is pad, layout identical to E2's LDS tile).
// ---------------------------------------------------------------------------
#define ENT 192
__global__ __launch_bounds__(ENT) void conv1_kernel(
    const float* __restrict__ images,
    const float* __restrict__ w1T, const float* __restrict__ b1,
    float* __restrict__ c1g, const int s0)
{
  __shared__ __align__(16) float buf[3072];
  const int bid = blockIdx.x;
  const int tid = threadIdx.x;
  {
    const float4* src = (const float4*)(images + (size_t)(s0 + bid) * 3072);
    float4* dst = (float4*)buf;
    for (int i = tid; i < 768; i += ENT) dst[i] = src[i];
  }
  __syncthreads();

  float* outp = c1g + (size_t)bid * 7680;
  for (int s = tid; s < 360; s += ENT) {
    const int ocg  = s & 7;
    const int pg   = s >> 3;
    const int row  = pg / 3;
    const int colg = pg - row * 3;
    const int ox0  = colg * 5;
    float acc[4][5];
    #pragma unroll
    for (int o = 0; o < 4; ++o) {
      const float bb = b1[ocg * 4 + o];
      #pragma unroll
      for (int p = 0; p < 5; ++p) acc[o][p] = bb;
    }
    #pragma unroll
    for (int ic = 0; ic < 3; ++ic) {
      #pragma unroll
      for (int ky = 0; ky < 4; ++ky) {
        const int y = 2 * row + ky;
        const float* ib = &buf[ic * 1024 + y * 32 + 2 * ox0];
        float v[12];
        #pragma unroll
        for (int i = 0; i < 6; ++i) { float2 t2 = *(const float2*)(ib + 2 * i); v[2*i] = t2.x; v[2*i+1] = t2.y; }
        float w_[4][4];
        #pragma unroll
        for (int kx = 0; kx < 4; ++kx)
          *(float4*)&w_[kx][0] = *(const float4*)(w1T + (ic * 16 + ky * 4 + kx) * 32 + ocg * 4);
        #pragma unroll
        for (int o = 0; o < 4; ++o)
          #pragma unroll
          for (int p = 0; p < 5; ++p)
            acc[o][p] += w_[0][o] * v[2*p] + w_[1][o] * v[2*p+1] + w_[2][o] * v[2*p+2] + w_[3][o] * v[2*p+3];
      }
    }
    #pragma unroll
    for (int o = 0; o < 4; ++o)
      #pragma unroll
      for (int p = 0; p < 5; ++p)
        outp[(ocg * 4 + o) * 240 + row * 16 + ox0 + p] = fmaxf(acc[o][p], 0.0f);
  }
}

// ---------------------------------------------------------------------------
// E2: conv2 + conv3 + linear, one block per sample. LDS: c1 [32][240] (30 KB)
// + c2 [64][38] (9.5 KB) = 40.0 KB -> 4 blocks/CU. psum/c3/linear reuse c1.
// ---------------------------------------------------------------------------
__global__ __launch_bounds__(ENT) void enc2_kernel(
    const float* __restrict__ c1g,
    const float* __restrict__ w2T, const float* __restrict__ b2,
    const float* __restrict__ w3T, const float* __restrict__ b3,
    const float* __restrict__ ewT, const float* __restrict__ eb,
    float* __restrict__ z_all, const int s0)
{
  __shared__ __align__(16) float c1[7680];
  __shared__ __align__(16) float buf[2432];
  const int bid = blockIdx.x;
  const int tid = threadIdx.x;

  {
    const float4* src = (const float4*)(c1g + (size_t)bid * 7680);
    float4* dst = (float4*)c1;
    for (int i = tid; i < 1920; i += ENT) dst[i] = src[i];
  }
  __syncthreads();

  // ---- conv2: 32->64, k4 s2, out 6x6, ReLU. tile = 4oc x 3pos. 192 slots.
  {
    const int ocg = tid & 15;
    const int pg  = tid >> 4;
    const int row = pg >> 1;
    const int ox0 = (pg & 1) * 3;
    float acc[4][3];
    #pragma unroll
    for (int o = 0; o < 4; ++o) {
      const float bb = b2[ocg * 4 + o];
      acc[o][0] = bb; acc[o][1] = bb; acc[o][2] = bb;
    }
    for (int ic = 0; ic < 32; ++ic) {
      #pragma unroll
      for (int ky = 0; ky < 4; ++ky) {
        const int y = 2 * row + ky;
        const float* ib = &c1[ic * 240 + y * 16 + 2 * ox0];
        float v[8];
        #pragma unroll
        for (int i = 0; i < 4; ++i) { float2 t2 = *(const float2*)(ib + 2 * i); v[2*i] = t2.x; v[2*i+1] = t2.y; }
        float w_[4][4];
        #pragma unroll
        for (int kx = 0; kx < 4; ++kx)
          *(float4*)&w_[kx][0] = *(const float4*)(w2T + (ic * 16 + ky * 4 + kx) * 64 + ocg * 4);
        #pragma unroll
        for (int o = 0; o < 4; ++o)
          #pragma unroll
          for (int p = 0; p < 3; ++p)
            acc[o][p] += w_[0][o] * v[2*p] + w_[1][o] * v[2*p+1] + w_[2][o] * v[2*p+2] + w_[3][o] * v[2*p+3];
      }
    }
    #pragma unroll
    for (int o = 0; o < 4; ++o)
      #pragma unroll
      for (int p = 0; p < 3; ++p)
        buf[(ocg * 4 + o) * 38 + row * 6 + ox0 + p] = fmaxf(acc[o][p], 0.0f);
  }
  __syncthreads();   // conv2 c1-reads + c2 writes complete

  // ---- conv3: 64->64, k4 s2, out 2x2, NO ReLU. thread = oc(64) x kc(3).
  {
    const int oc = tid & 63;
    const int kc = tid >> 6;
    const int k0 = (kc * 256) / 3, k1 = ((kc + 1) * 256) / 3;
    float acc[4] = {0.f, 0.f, 0.f, 0.f};
    for (int it = k0; it < k1; ++it) {
      const int ic = it >> 2;
      const int ky = it & 3;
      float v[2][6];
      #pragma unroll
      for (int oy = 0; oy < 2; ++oy) {
        const float* ib = &buf[ic * 38 + (2 * oy + ky) * 6];
        #pragma unroll
        for (int i = 0; i < 3; ++i) { float2 t2 = *(const float2*)(ib + 2 * i); v[oy][2*i] = t2.x; v[oy][2*i+1] = t2.y; }
      }
      float w_[4];
      #pragma unroll
      for (int kx = 0; kx < 4; ++kx) w_[kx] = w3T[(ic * 16 + ky * 4 + kx) * 64 + oc];
      #pragma unroll
      for (int p = 0; p < 4; ++p) {
        const int oy = p >> 1, ox = p & 1;
        acc[p] += w_[0] * v[oy][2*ox] + w_[1] * v[oy][2*ox+1] + w_[2] * v[oy][2*ox+2] + w_[3] * v[oy][2*ox+3];
      }
    }
    #pragma unroll
    for (int p = 0; p < 4; ++p) c1[kc * 260 + p * 64 + oc] = acc[p];
  }
  __syncthreads();

  for (int o = tid; o < 256; o += ENT) {
    const int oc = o >> 2, p = o & 3;
    c1[1024 + o] = b3[oc] + c1[p * 64 + oc] + c1[260 + p * 64 + oc] + c1[520 + p * 64 + oc];
  }
  __syncthreads();

  {
    const int d  = tid & 63;
    const int kc = tid >> 6;
    const int k0 = (kc * 256) / 3, k1 = ((kc + 1) * 256) / 3;
    float s = 0.0f;
    for (int k = k0; k < k1; ++k) s += ewT[k * 64 + d] * c1[1024 + k];
    c1[1536 + kc * 64 + d] = s;
  }
  __syncthreads();
  if (tid < 64) {
    z_all[(size_t)(s0 + bid) * 64 + tid] = eb[tid] + c1[1536 + tid] + c1[1600 + tid] + c1[1664 + tid];
  }
}

// ---------------------------------------------------------------------------
// Monolithic encoder fallback (R3) if ws can't hold c1g chunks.
// ---------------------------------------------------------------------------
__global__ __launch_bounds__(ENT) void encoder_kernel(
    const float* __restrict__ images,
    const float* __restrict__ w1T, const float* __restrict__ b1,
    const float* __restrict__ w2T, const float* __restrict__ b2,
    const float* __restrict__ w3T, const float* __restrict__ b3,
    const float* __restrict__ ewT, const float* __restrict__ eb,
    float* __restrict__ z_all)
{
  __shared__ __align__(16) float c1[7744];
  __shared__ __align__(16) float buf[3072];
  const int bid = blockIdx.x;
  const int tid = threadIdx.x;
  {
    const float4* src = (const float4*)(images + (size_t)bid * 3072);
    float4* dst = (float4*)buf;
    for (int i = tid; i < 768; i += ENT) dst[i] = src[i];
  }
  __syncthreads();
  for (int s = tid; s < 360; s += ENT) {
    const int ocg  = s & 7;
    const int pg   = s >> 3;
    const int row  = pg / 3;
    const int colg = pg - row * 3;
    const int ox0  = colg * 5;
    float acc[4][5];
    #pragma unroll
    for (int o = 0; o < 4; ++o) {
      const float bb = b1[ocg * 4 + o];
      #pragma unroll
      for (int p = 0; p < 5; ++p) acc[o][p] = bb;
    }
    #pragma unroll
    for (int ic = 0; ic < 3; ++ic) {
      #pragma unroll
      for (int ky = 0; ky < 4; ++ky) {
        const int y = 2 * row + ky;
        const float* ib = &buf[ic * 1024 + y * 32 + 2 * ox0];
        float v[12];
        #pragma unroll
        for (int i = 0; i < 6; ++i) { float2 t2 = *(const float2*)(ib + 2 * i); v[2*i] = t2.x; v[2*i+1] = t2.y; }
        float w_[4][4];
        #pragma unroll
        for (int kx = 0; kx < 4; ++kx)
          *(float4*)&w_[kx][0] = *(const float4*)(w1T + (ic * 16 + ky * 4 + kx) * 32 + ocg * 4);
        #pragma unroll
        for (int o = 0; o < 4; ++o)
          #pragma unroll
          for (int p = 0; p < 5; ++p)
            acc[o][p] += w_[0][o] * v[2*p] + w_[1][o] * v[2*p+1] + w_[2][o] * v[2*p+2] + w_[3][o] * v[2*p+3];
      }
    }
    #pragma unroll
    for (int o = 0; o < 4; ++o)
      #pragma unroll
      for (int p = 0; p < 5; ++p)
        c1[(ocg * 4 + o) * 242 + row * 16 + ox0 + p] = fmaxf(acc[o][p], 0.0f);
  }
  __syncthreads();
  {
    const int ocg = tid & 15;
    const int pg  = tid >> 4;
    const int row = pg >> 1;
    const int ox0 = (pg & 1) * 3;
    float acc[4][3];
    #pragma unroll
    for (int o = 0; o < 4; ++o) {
      const float bb = b2[ocg * 4 + o];
      acc[o][0] = bb; acc[o][1] = bb; acc[o][2] = bb;
    }
    for (int ic = 0; ic < 32; ++ic) {
      #pragma unroll
      for (int ky = 0; ky < 4; ++ky) {
        const int y = 2 * row + ky;
        const float* ib = &c1[ic * 242 + y * 16 + 2 * ox0];
        float v[8];
        #pragma unroll
        for (int i = 0; i < 4; ++i) { float2 t2 = *(const float2*)(ib + 2 * i); v[2*i] = t2.x; v[2*i+1] = t2.y; }
        float w_[4][4];
        #pragma unroll
        for (int kx = 0; kx < 4; ++kx)
          *(float4*)&w_[kx][0] = *(const float4*)(w2T + (ic * 16 + ky * 4 + kx) * 64 + ocg * 4);
        #pragma unroll
        for (int o = 0; o < 4; ++o)
          #pragma unroll
          for (int p = 0; p < 3; ++p)
            acc[o][p] += w_[0][o] * v[2*p] + w_[1][o] * v[2*p+1] + w_[2][o] * v[2*p+2] + w_[3][o] * v[2*p+3];
      }
    }
    __syncthreads();
    #pragma unroll
    for (int o = 0; o < 4; ++o)
      #pragma unroll
      for (int p = 0; p < 3; ++p)
        buf[(ocg * 4 + o) * 38 + row * 6 + ox0 + p] = fmaxf(acc[o][p], 0.0f);
  }
  __syncthreads();
  {
    const int oc = tid & 63;
    const int kc = tid >> 6;
    const int k0 = (kc * 256) / 3, k1 = ((kc + 1) * 256) / 3;
    float acc[4] = {0.f, 0.f, 0.f, 0.f};
    for (int it = k0; it < k1; ++it) {
      const int ic = it >> 2;
      const int ky = it & 3;
      float v[2][6];
      #pragma unroll
      for (int oy = 0; oy < 2; ++oy) {
        const float* ib = &buf[ic * 38 + (2 * oy + ky) * 6];
        #pragma unroll
        for (int i = 0; i < 3; ++i) { float2 t2 = *(const float2*)(ib + 2 * i); v[oy][2*i] = t2.x; v[oy][2*i+1] = t2.y; }
      }
      float w_[4];
      #pragma unroll
      for (int kx = 0; kx < 4; ++kx) w_[kx] = w3T[(ic * 16 + ky * 4 + kx) * 64 + oc];
      #pragma unroll
      for (int p = 0; p < 4; ++p) {
        const int oy = p >> 1, ox = p & 1;
        acc[p] += w_[0] * v[oy][2*ox] + w_[1] * v[oy][2*ox+1] + w_[2] * v[oy][2*ox+2] + w_[3] * v[oy][2*ox+3];
      }
    }
    #pragma unroll
    for (int p = 0; p < 4; ++p) c1[kc * 260 + p * 64 + oc] = acc[p];
  }
  __syncthreads();
  for (int o = tid; o < 256; o += ENT) {
    const int oc = o >> 2, p = o & 3;
    c1[1024 + o] = b3[oc] + c1[p * 64 + oc] + c1[260 + p * 64 + oc] + c1[520 + p * 64 + oc];
  }
  __syncthreads();
  {
    const int d  = tid & 63;
    const int kc = tid >> 6;
    const int k0 = (kc * 256) / 3, k1 = ((kc + 1) * 256) / 3;
    float s = 0.0f;
    for (int k = k0; k < k1; ++k) s += ewT[k * 64 + d] * c1[1024 + k];
    c1[1536 + kc * 64 + d] = s;
  }
  __syncthreads();
  if (tid < 64) {
    z_all[(size_t)bid * 64 + tid] = eb[tid] + c1[1536 + tid] + c1[1600 + tid] + c1[1664 + tid];
  }
}

// ---------------------------------------------------------------------------
// z-Gram: z_gram[b][t][n] = z_t . z_n
// ---------------------------------------------------------------------------
__global__ __launch_bounds__(256) void gram_kernel(
    const float* __restrict__ z_all, float* __restrict__ z_gram)
{
  const int b = blockIdx.x;
  const int tid = threadIdx.x;
  __shared__ float zsb[64 * 65];
  for (int i = tid; i < 4096; i += 256) {
    const int tt = i >> 6, d = i & 63;
    zsb[tt * 65 + d] = z_all[((size_t)tt * 256 + b) * 64 + d];
  }
  __syncthreads();
  const int n = tid & 63, tg = tid >> 6;
  for (int tt = tg; tt < 64; tt += 4) {
    float s = 0.0f;
    #pragma unroll
    for (int d = 0; d < 64; ++d) s += zsb[tt * 65 + d] * zsb[n * 65 + d];
    z_gram[((size_t)b * 64 + tt) * 64 + n] = s;
  }
}

// ---------------------------------------------------------------------------
// Persistent cooperative scan: all 64 steps in one kernel.
// grid = 128*kcn blocks (<= 2/CU co-resident), 256 threads.
// Phase A: Gp[kc][256][2048] = XC[:,k-slice] @ WT[k-slice,:]   (all blocks)
// Phase B: per-b LSTM elementwise + dots + softmax + memory read (blocks<256)
// Two grid.sync() per step.
// ---------------------------------------------------------------------------
__global__ __launch_bounds__(256, 2) void scan_coop_kernel(
    const float* __restrict__ WT, const float* __restrict__ bsum,
    float* __restrict__ C, const float* __restrict__ z_gram,
    float* __restrict__ MkT, float* __restrict__ XC, float* __restrict__ Gp,
    float* __restrict__ o_ptr,
    const float* __restrict__ out_w, const float* __restrict__ out_b,
    const float* __restrict__ gate_w, const float* __restrict__ gate_b,
    const float* __restrict__ key_w, const float* __restrict__ key_b,
    const float* __restrict__ conf_w, const float* __restrict__ conf_b,
    const int kcn, const int klog, const int kchunk)
{
  cg::grid_group grid = cg::this_grid();
  __shared__ __align__(16) float smem[16 * 580];   // phase A stage / phase B scratch

  const int tid = threadIdx.x;
  const int gid = blockIdx.x;
  const int jt  = gid & 7;
  const int kc  = (gid >> 3) & (kcn - 1);
  const int bt  = gid >> (3 + klog);
  const int tj  = tid & 63, tb = tid >> 6;
  const int k0  = kc * kchunk;
  const int b0  = bt * 16;
  const int j0  = jt * 256 + tj * 4;
  const int NS  = 16 * kchunk;

  for (int t = 0; t < 64; ++t) {
    // ---- phase A: gates partial GEMM
    for (int i = tid; i < NS; i += 256) {
      const int b = i / kchunk, k = i - b * kchunk;
      smem[b * kchunk + k] = XC[(size_t)(b0 + b) * 580 + k0 + k];
    }
    __syncthreads();
    {
      float acc[4][4];
      #pragma unroll
      for (int bb = 0; bb < 4; ++bb) { acc[bb][0]=0.f; acc[bb][1]=0.f; acc[bb][2]=0.f; acc[bb][3]=0.f; }
      const float* wp = WT + (size_t)k0 * 2048 + j0;
      const float* xp = smem + tb * 4 * kchunk;
      #pragma unroll 4
      for (int k = 0; k < kchunk; ++k) {
        const float4 w = *(const float4*)(wp + (size_t)k * 2048);
        #pragma unroll
        for (int bb = 0; bb < 4; ++bb) {
          const float xv = xp[bb * kchunk + k];
          acc[bb][0] += xv * w.x; acc[bb][1] += xv * w.y;
          acc[bb][2] += xv * w.z; acc[bb][3] += xv * w.w;
        }
      }
      #pragma unroll
      for (int bb = 0; bb < 4; ++bb) {
        float4 r; r.x = acc[bb][0]; r.y = acc[bb][1]; r.z = acc[bb][2]; r.w = acc[bb][3];
        *(float4*)(Gp + ((size_t)kc * 256 + b0 + tb * 4 + bb) * 2048 + j0) = r;
      }
    }
    grid.sync();

    // ---- phase B: per-batch step
    for (int b = gid; b < 256; b += gridDim.x) {
      float* hs   = smem;          // 512
      float* wks  = smem + 512;    // 64
      float* psum = smem + 576;    // 256
      float* sgp  = smem + 832;    // 1
      float* kxp  = smem + 833;    // 1
      __syncthreads();             // smem role switch
      for (int jj = tid; jj < 512; jj += 256) {
        float gv[4];
        #pragma unroll
        for (int g = 0; g < 4; ++g) {
          float s = bsum[g * 512 + jj];
          for (int kc2 = 0; kc2 < kcn; ++kc2)
            s += Gp[((size_t)kc2 * 256 + b) * 2048 + g * 512 + jj];
          gv[g] = s;
        }
        const size_t cidx = (size_t)b * 512 + jj;
        const float c2v = sigm(gv[1]) * C[cidx] + sigm(gv[0]) * tanhf(gv[2]);
        C[cidx] = c2v;
        const float h = sigm(gv[3]) * tanhf(c2v);
        hs[jj] = h;
        XC[(size_t)b * 580 + 65 + jj] = h;
      }
      __syncthreads();

      const int wv = tid >> 6, lane = tid & 63;
      for (int d = wv; d < 69; d += 4) {
        const float* row = (d < 64) ? (key_w + (size_t)d * 512)
                         : (d < 68) ? (out_w + (size_t)(d - 64) * 512)
                                    : gate_w;
        float a = 0.0f;
        #pragma unroll
        for (int k = 0; k < 8; ++k) a += hs[lane + k * 64] * row[lane + k * 64];
        #pragma unroll
        for (int m = 32; m > 0; m >>= 1) a += __shfl_xor(a, m);
        if (lane == 0) {
          if (d < 64)      MkT[(size_t)b * 4096 + d * 64 + t] = a + key_b[d];
          else if (d < 68) o_ptr[(size_t)t * 1024 + b * 4 + (d - 64)] = a + out_b[d - 64];
          else             *sgp = sigm(a + gate_b[0]);
        }
      }
      __syncthreads();

      if (t == 0) {
        if (tid < 65) XC[(size_t)b * 580 + tid] = 0.0f;
      } else {
        if (tid < 64) {
          const int n = tid;
          const float sim = z_gram[((size_t)b * 64 + t) * 64 + n];
          const bool valid = (n < t);
          float mx = valid ? sim : -3.0e38f;
          #pragma unroll
          for (int m = 32; m > 0; m >>= 1) mx = fmaxf(mx, __shfl_xor(mx, m));
          const float p = valid ? expf(sim - mx) : 0.0f;
          float sum = p;
          #pragma unroll
          for (int m = 32; m > 0; m >>= 1) sum += __shfl_xor(sum, m);
          const float wk = p / sum;
          wks[n] = wk;
          float kcv = wk * sigm(sim * conf_w[0] + conf_b[0]);
          #pragma unroll
          for (int m = 32; m > 0; m >>= 1) kcv += __shfl_xor(kcv, m);
          if (n == 0) *kxp = kcv;
        }
        __syncthreads();
        {
          const int d = tid >> 2, q = tid & 3;
          const float* mr = MkT + (size_t)b * 4096 + d * 64 + q * 16;
          const float* wr = wks + q * 16;
          float a = 0.0f;
          #pragma unroll
          for (int i = 0; i < 4; ++i) {
            const float4 m4 = *(const float4*)(mr + 4 * i);
            const float4 w4 = *(const float4*)(wr + 4 * i);
            a += m4.x * w4.x + m4.y * w4.y + m4.z * w4.z + m4.w * w4.w;
          }
          psum[tid] = a;
        }
        __syncthreads();
        if (tid < 64) {
          XC[(size_t)b * 580 + tid] = (*sgp) * (psum[tid * 4] + psum[tid * 4 + 1] + psum[tid * 4 + 2] + psum[tid * 4 + 3]);
        } else if (tid == 64) {
          XC[(size_t)b * 580 + 64] = (*sgp) * (*kxp);
        }
      }
    }
    grid.sync();
  }
}

// ---------------------------------------------------------------------------
extern "C" void kernel_launch(void* const* d_in, const int* in_sizes, int n_in,
                              void* d_out, int out_size, void* d_ws, size_t ws_size,
                              hipStream_t stream) {
  const float* images = (const float*)d_in[0];
  const float* w1     = (const float*)d_in[1];
  const float* b1     = (const float*)d_in[2];
  const float* w2     = (const float*)d_in[3];
  const float* b2     = (const float*)d_in[4];
  const float* w3     = (const float*)d_in[5];
  const float* b3     = (const float*)d_in[6];
  const float* ew     = (const float*)d_in[7];
  const float* eb     = (const float*)d_in[8];
  const float* w_ih   = (const float*)d_in[9];
  const float* w_hh   = (const float*)d_in[10];
  const float* b_ih   = (const float*)d_in[11];
  const float* b_hh   = (const float*)d_in[12];
  const float* out_w  = (const float*)d_in[13];
  const float* out_b  = (const float*)d_in[14];
  const float* gate_w = (const float*)d_in[15];
  const float* gate_b = (const float*)d_in[16];
  const float* key_w  = (const float*)d_in[17];
  const float* key_b  = (const float*)d_in[18];
  const float* conf_w = (const float*)d_in[19];
  const float* conf_b = (const float*)d_in[20];
  float* o_ptr = (float*)d_out;
  float* ws    = (float*)d_ws;

  // ws layout (floats)
  float* WT     = ws;                  // 1,187,840
  float* bsum   = ws + 1187840;        // 2,048
  float* w1T    = ws + 1189888;        // 1,536
  float* w2T    = ws + 1191424;        // 32,768
  float* w3T    = ws + 1224192;        // 65,536
  float* ewT    = ws + 1289728;        // 16,384
  float* z_all  = ws + 1306112;        // 1,048,576
  float* MkT    = ws + 2354688;        // 1,048,576
  float* C      = ws + 3403264;        // 131,072
  float* XC     = ws + 3534336;        // 148,480
  float* z_gram = ws + 3682816;        // 1,048,576
  float* Gp     = ws + 4731392;        // kcn * 524,288

  int kcn = 4, klog = 2, kchunk = 145;
  if (ws_size < (4731392ull + 4ull * 524288ull) * 4ull) { kcn = 2; klog = 1; kchunk = 290; }
  if (ws_size < (4731392ull + 2ull * 524288ull) * 4ull) { kcn = 1; klog = 0; kchunk = 580; }

  const size_t baseF  = 4731392ull + (size_t)kcn * 524288ull;
  float* c1g          = ws + baseF;
  const size_t availF = (ws_size / 4 > baseF) ? (ws_size / 4 - baseF) : 0;
  long chunkL = (long)(availF / 7680ull);
  int chunk = (chunkL > 16384) ? 16384 : (int)chunkL;

  hipMemsetAsync(C,  0, 131072 * sizeof(float), stream);
  hipMemsetAsync(XC, 0, 148480 * sizeof(float), stream);

  prep_kernel<<<(PREP_N + 255) / 256, 256, 0, stream>>>(
      w_ih, w_hh, b_ih, b_hh, w1, w2, w3, ew, WT, bsum, w1T, w2T, w3T, ewT);

  if (chunk >= 2048) {
    for (int s0 = 0; s0 < 16384; s0 += chunk) {
      const int n = (16384 - s0 < chunk) ? (16384 - s0) : chunk;
      conv1_kernel<<<n, ENT, 0, stream>>>(images, w1T, b1, c1g, s0);
      enc2_kernel<<<n, ENT, 0, stream>>>(c1g, w2T, b2, w3T, b3, ewT, eb, z_all, s0);
    }
  } else {
    encoder_kernel<<<16384, ENT, 0, stream>>>(images, w1T, b1, w2T, b2, w3T, b3, ewT, eb, z_all);
  }

  gram_kernel<<<256, 256, 0, stream>>>(z_all, z_gram);

  void* args[] = { (void*)&WT, (void*)&bsum, (void*)&C, (void*)&z_gram,
                   (void*)&MkT, (void*)&XC, (void*)&Gp, (void*)&o_ptr,
                   (void*)&out_w, (void*)&out_b, (void*)&gate_w, (void*)&gate_b,
                   (void*)&key_w, (void*)&key_b, (void*)&conf_w, (void*)&conf_b,
                   (void*)&kcn, (void*)&klog, (void*)&kchunk };
  hipLaunchCooperativeKernel((void*)scan_coop_kernel, dim3(128 * kcn), dim3(256),
                             args, 0, stream);
}

// Round 6
// 4190.522 us; speedup vs baseline: 2.6969x; 2.6969x over previous
//
#include <hip/hip_runtime.h>
#include <math.h>

// ESBN: encoder (conv x3 + linear) + 64-step LSTM/memory scan. fp32.
// R6: split encoder (conv1 | conv2/3/linear) kept from R5; scan reverted to
// two-kernel-per-step (R4) — grid.sync cost ~75us + L2 flush per sync on
// 8-XCD MI355X (measured R5: 1GB HBM traffic/dispatch). Gates GEMM stage
// transposed to xs[k][16b] for float4 X reads.

__device__ __forceinline__ float sigm(float x) { return 1.0f / (1.0f + expf(-x)); }

// ---------------------------------------------------------------------------
// prep: transposed weights in ws.
//   WT [580][2048] (rows 0..64 w_ih^T, 65..576 w_hh^T, 577..579 zero),
//   bsum[2048], w1T[48][32], w2T[512][64], w3T[1024][64], ewT[256][64]
// ---------------------------------------------------------------------------
#define PREP_N (1187840 + 2048 + 1536 + 32768 + 65536 + 16384)
__global__ __launch_bounds__(256) void prep_kernel(
    const float* __restrict__ w_ih, const float* __restrict__ w_hh,
    const float* __restrict__ b_ih, const float* __restrict__ b_hh,
    const float* __restrict__ w1, const float* __restrict__ w2,
    const float* __restrict__ w3, const float* __restrict__ ew,
    float* __restrict__ WT, float* __restrict__ bsum,
    float* __restrict__ w1T, float* __restrict__ w2T,
    float* __restrict__ w3T, float* __restrict__ ewT)
{
  int i = blockIdx.x * 256 + threadIdx.x;
  if (i < 1187840) {
    const int r = i >> 11, c = i & 2047;
    float v;
    if (r < 65)       v = w_ih[(size_t)c * 65 + r];
    else if (r < 577) v = w_hh[(size_t)c * 512 + (r - 65)];
    else              v = 0.0f;
    WT[i] = v; return;
  }
  i -= 1187840;
  if (i < 2048) { bsum[i] = b_ih[i] + b_hh[i]; return; }
  i -= 2048;
  if (i < 1536) { const int r = i >> 5, oc = i & 31; w1T[i] = w1[oc * 48 + r]; return; }
  i -= 1536;
  if (i < 32768) { const int r = i >> 6, oc = i & 63; w2T[i] = w2[oc * 512 + r]; return; }
  i -= 32768;
  if (i < 65536) { const int r = i >> 6, oc = i & 63; w3T[i] = w3[oc * 1024 + r]; return; }
  i -= 65536;
  if (i < 16384) { const int k = i >> 6, d = i & 63; ewT[i] = ew[d * 256 + k]; return; }
}

// ---------------------------------------------------------------------------
// E1: conv1 only (3->32, k4 s2, out 15x15, ReLU), one block per sample.
// LDS = image only (12 KB). Output c1g[bid][32][240] (row stride 16).
// ---------------------------------------------------------------------------
#define ENT 192
__global__ __launch_bounds__(ENT) void conv1_kernel(
    const float* __restrict__ images,
    const float* __restrict__ w1T, const float* __restrict__ b1,
    float* __restrict__ c1g, const int s0)
{
  __shared__ __align__(16) float buf[3072];
  const int bid = blockIdx.x;
  const int tid = threadIdx.x;
  {
    const float4* src = (const float4*)(images + (size_t)(s0 + bid) * 3072);
    float4* dst = (float4*)buf;
    for (int i = tid; i < 768; i += ENT) dst[i] = src[i];
  }
  __syncthreads();

  float* outp = c1g + (size_t)bid * 7680;
  for (int s = tid; s < 360; s += ENT) {
    const int ocg  = s & 7;
    const int pg   = s >> 3;
    const int row  = pg / 3;
    const int colg = pg - row * 3;
    const int ox0  = colg * 5;
    float acc[4][5];
    #pragma unroll
    for (int o = 0; o < 4; ++o) {
      const float bb = b1[ocg * 4 + o];
      #pragma unroll
      for (int p = 0; p < 5; ++p) acc[o][p] = bb;
    }
    #pragma unroll
    for (int ic = 0; ic < 3; ++ic) {
      #pragma unroll
      for (int ky = 0; ky < 4; ++ky) {
        const int y = 2 * row + ky;
        const float* ib = &buf[ic * 1024 + y * 32 + 2 * ox0];
        float v[12];
        #pragma unroll
        for (int i = 0; i < 6; ++i) { float2 t2 = *(const float2*)(ib + 2 * i); v[2*i] = t2.x; v[2*i+1] = t2.y; }
        float w_[4][4];
        #pragma unroll
        for (int kx = 0; kx < 4; ++kx)
          *(float4*)&w_[kx][0] = *(const float4*)(w1T + (ic * 16 + ky * 4 + kx) * 32 + ocg * 4);
        #pragma unroll
        for (int o = 0; o < 4; ++o)
          #pragma unroll
          for (int p = 0; p < 5; ++p)
            acc[o][p] += w_[0][o] * v[2*p] + w_[1][o] * v[2*p+1] + w_[2][o] * v[2*p+2] + w_[3][o] * v[2*p+3];
      }
    }
    #pragma unroll
    for (int o = 0; o < 4; ++o)
      #pragma unroll
      for (int p = 0; p < 5; ++p)
        outp[(ocg * 4 + o) * 240 + row * 16 + ox0 + p] = fmaxf(acc[o][p], 0.0f);
  }
}

// ---------------------------------------------------------------------------
// E2: conv2 + conv3 + linear, one block per sample.
// LDS: c1 [32][240] (30 KB) + c2 [64][37] (9.25 KB) = 40,192 B -> 4 blk/CU.
// ---------------------------------------------------------------------------
__global__ __launch_bounds__(ENT) void enc2_kernel(
    const float* __restrict__ c1g,
    const float* __restrict__ w2T, const float* __restrict__ b2,
    const float* __restrict__ w3T, const float* __restrict__ b3,
    const float* __restrict__ ewT, const float* __restrict__ eb,
    float* __restrict__ z_all, const int s0)
{
  __shared__ __align__(16) float c1[7680];
  __shared__ __align__(16) float buf[2368];
  const int bid = blockIdx.x;
  const int tid = threadIdx.x;

  {
    const float4* src = (const float4*)(c1g + (size_t)bid * 7680);
    float4* dst = (float4*)c1;
    for (int i = tid; i < 1920; i += ENT) dst[i] = src[i];
  }
  __syncthreads();

  // ---- conv2: 32->64, k4 s2, out 6x6, ReLU. tile = 4oc x 3pos. 192 slots.
  {
    const int ocg = tid & 15;
    const int pg  = tid >> 4;
    const int row = pg >> 1;
    const int ox0 = (pg & 1) * 3;
    float acc[4][3];
    #pragma unroll
    for (int o = 0; o < 4; ++o) {
      const float bb = b2[ocg * 4 + o];
      acc[o][0] = bb; acc[o][1] = bb; acc[o][2] = bb;
    }
    for (int ic = 0; ic < 32; ++ic) {
      #pragma unroll
      for (int ky = 0; ky < 4; ++ky) {
        const int y = 2 * row + ky;
        const float* ib = &c1[ic * 240 + y * 16 + 2 * ox0];
        float v[8];
        #pragma unroll
        for (int i = 0; i < 4; ++i) { float2 t2 = *(const float2*)(ib + 2 * i); v[2*i] = t2.x; v[2*i+1] = t2.y; }
        float w_[4][4];
        #pragma unroll
        for (int kx = 0; kx < 4; ++kx)
          *(float4*)&w_[kx][0] = *(const float4*)(w2T + (ic * 16 + ky * 4 + kx) * 64 + ocg * 4);
        #pragma unroll
        for (int o = 0; o < 4; ++o)
          #pragma unroll
          for (int p = 0; p < 3; ++p)
            acc[o][p] += w_[0][o] * v[2*p] + w_[1][o] * v[2*p+1] + w_[2][o] * v[2*p+2] + w_[3][o] * v[2*p+3];
      }
    }
    #pragma unroll
    for (int o = 0; o < 4; ++o)
      #pragma unroll
      for (int p = 0; p < 3; ++p)
        buf[(ocg * 4 + o) * 37 + row * 6 + ox0 + p] = fmaxf(acc[o][p], 0.0f);
  }
  __syncthreads();   // conv2 c1-reads + c2 writes complete

  // ---- conv3: 64->64, k4 s2, out 2x2, NO ReLU. thread = oc(64) x kc(3).
  {
    const int oc = tid & 63;
    const int kc = tid >> 6;
    const int k0 = (kc * 256) / 3, k1 = ((kc + 1) * 256) / 3;
    float acc[4] = {0.f, 0.f, 0.f, 0.f};
    for (int it = k0; it < k1; ++it) {
      const int ic = it >> 2;
      const int ky = it & 3;
      float v[2][6];
      #pragma unroll
      for (int oy = 0; oy < 2; ++oy) {
        const float* ib = &buf[ic * 37 + (2 * oy + ky) * 6];
        #pragma unroll
        for (int i = 0; i < 3; ++i) { float2 t2 = *(const float2*)(ib + 2 * i); v[oy][2*i] = t2.x; v[oy][2*i+1] = t2.y; }
      }
      float w_[4];
      #pragma unroll
      for (int kx = 0; kx < 4; ++kx) w_[kx] = w3T[(ic * 16 + ky * 4 + kx) * 64 + oc];
      #pragma unroll
      for (int p = 0; p < 4; ++p) {
        const int oy = p >> 1, ox = p & 1;
        acc[p] += w_[0] * v[oy][2*ox] + w_[1] * v[oy][2*ox+1] + w_[2] * v[oy][2*ox+2] + w_[3] * v[oy][2*ox+3];
      }
    }
    #pragma unroll
    for (int p = 0; p < 4; ++p) c1[kc * 260 + p * 64 + oc] = acc[p];
  }
  __syncthreads();

  for (int o = tid; o < 256; o += ENT) {
    const int oc = o >> 2, p = o & 3;
    c1[1024 + o] = b3[oc] + c1[p * 64 + oc] + c1[260 + p * 64 + oc] + c1[520 + p * 64 + oc];
  }
  __syncthreads();

  {
    const int d  = tid & 63;
    const int kc = tid >> 6;
    const int k0 = (kc * 256) / 3, k1 = ((kc + 1) * 256) / 3;
    float s = 0.0f;
    for (int k = k0; k < k1; ++k) s += ewT[k * 64 + d] * c1[1024 + k];
    c1[1536 + kc * 64 + d] = s;
  }
  __syncthreads();
  if (tid < 64) {
    z_all[(size_t)(s0 + bid) * 64 + tid] = eb[tid] + c1[1536 + tid] + c1[1600 + tid] + c1[1664 + tid];
  }
}

// ---------------------------------------------------------------------------
// Monolithic encoder fallback (if ws can't hold c1g chunks).
// ---------------------------------------------------------------------------
__global__ __launch_bounds__(ENT) void encoder_kernel(
    const float* __restrict__ images,
    const float* __restrict__ w1T, const float* __restrict__ b1,
    const float* __restrict__ w2T, const float* __restrict__ b2,
    const float* __restrict__ w3T, const float* __restrict__ b3,
    const float* __restrict__ ewT, const float* __restrict__ eb,
    float* __restrict__ z_all)
{
  __shared__ __align__(16) float c1[7744];
  __shared__ __align__(16) float buf[3072];
  const int bid = blockIdx.x;
  const int tid = threadIdx.x;
  {
    const float4* src = (const float4*)(images + (size_t)bid * 3072);
    float4* dst = (float4*)buf;
    for (int i = tid; i < 768; i += ENT) dst[i] = src[i];
  }
  __syncthreads();
  for (int s = tid; s < 360; s += ENT) {
    const int ocg  = s & 7;
    const int pg   = s >> 3;
    const int row  = pg / 3;
    const int colg = pg - row * 3;
    const int ox0  = colg * 5;
    float acc[4][5];
    #pragma unroll
    for (int o = 0; o < 4; ++o) {
      const float bb = b1[ocg * 4 + o];
      #pragma unroll
      for (int p = 0; p < 5; ++p) acc[o][p] = bb;
    }
    #pragma unroll
    for (int ic = 0; ic < 3; ++ic) {
      #pragma unroll
      for (int ky = 0; ky < 4; ++ky) {
        const int y = 2 * row + ky;
        const float* ib = &buf[ic * 1024 + y * 32 + 2 * ox0];
        float v[12];
        #pragma unroll
        for (int i = 0; i < 6; ++i) { float2 t2 = *(const float2*)(ib + 2 * i); v[2*i] = t2.x; v[2*i+1] = t2.y; }
        float w_[4][4];
        #pragma unroll
        for (int kx = 0; kx < 4; ++kx)
          *(float4*)&w_[kx][0] = *(const float4*)(w1T + (ic * 16 + ky * 4 + kx) * 32 + ocg * 4);
        #pragma unroll
        for (int o = 0; o < 4; ++o)
          #pragma unroll
          for (int p = 0; p < 5; ++p)
            acc[o][p] += w_[0][o] * v[2*p] + w_[1][o] * v[2*p+1] + w_[2][o] * v[2*p+2] + w_[3][o] * v[2*p+3];
      }
    }
    #pragma unroll
    for (int o = 0; o < 4; ++o)
      #pragma unroll
      for (int p = 0; p < 5; ++p)
        c1[(ocg * 4 + o) * 242 + row * 16 + ox0 + p] = fmaxf(acc[o][p], 0.0f);
  }
  __syncthreads();
  {
    const int ocg = tid & 15;
    const int pg  = tid >> 4;
    const int row = pg >> 1;
    const int ox0 = (pg & 1) * 3;
    float acc[4][3];
    #pragma unroll
    for (int o = 0; o < 4; ++o) {
      const float bb = b2[ocg * 4 + o];
      acc[o][0] = bb; acc[o][1] = bb; acc[o][2] = bb;
    }
    for (int ic = 0; ic < 32; ++ic) {
      #pragma unroll
      for (int ky = 0; ky < 4; ++ky) {
        const int y = 2 * row + ky;
        const float* ib = &c1[ic * 242 + y * 16 + 2 * ox0];
        float v[8];
        #pragma unroll
        for (int i = 0; i < 4; ++i) { float2 t2 = *(const float2*)(ib + 2 * i); v[2*i] = t2.x; v[2*i+1] = t2.y; }
        float w_[4][4];
        #pragma unroll
        for (int kx = 0; kx < 4; ++kx)
          *(float4*)&w_[kx][0] = *(const float4*)(w2T + (ic * 16 + ky * 4 + kx) * 64 + ocg * 4);
        #pragma unroll
        for (int o = 0; o < 4; ++o)
          #pragma unroll
          for (int p = 0; p < 3; ++p)
            acc[o][p] += w_[0][o] * v[2*p] + w_[1][o] * v[2*p+1] + w_[2][o] * v[2*p+2] + w_[3][o] * v[2*p+3];
      }
    }
    __syncthreads();
    #pragma unroll
    for (int o = 0; o < 4; ++o)
      #pragma unroll
      for (int p = 0; p < 3; ++p)
        buf[(ocg * 4 + o) * 38 + row * 6 + ox0 + p] = fmaxf(acc[o][p], 0.0f);
  }
  __syncthreads();
  {
    const int oc = tid & 63;
    const int kc = tid >> 6;
    const int k0 = (kc * 256) / 3, k1 = ((kc + 1) * 256) / 3;
    float acc[4] = {0.f, 0.f, 0.f, 0.f};
    for (int it = k0; it < k1; ++it) {
      const int ic = it >> 2;
      const int ky = it & 3;
      float v[2][6];
      #pragma unroll
      for (int oy = 0; oy < 2; ++oy) {
        const float* ib = &buf[ic * 38 + (2 * oy + ky) * 6];
        #pragma unroll
        for (int i = 0; i < 3; ++i) { float2 t2 = *(const float2*)(ib + 2 * i); v[oy][2*i] = t2.x; v[oy][2*i+1] = t2.y; }
      }
      float w_[4];
      #pragma unroll
      for (int kx = 0; kx < 4; ++kx) w_[kx] = w3T[(ic * 16 + ky * 4 + kx) * 64 + oc];
      #pragma unroll
      for (int p = 0; p < 4; ++p) {
        const int oy = p >> 1, ox = p & 1;
        acc[p] += w_[0] * v[oy][2*ox] + w_[1] * v[oy][2*ox+1] + w_[2] * v[oy][2*ox+2] + w_[3] * v[oy][2*ox+3];
      }
    }
    #pragma unroll
    for (int p = 0; p < 4; ++p) c1[kc * 260 + p * 64 + oc] = acc[p];
  }
  __syncthreads();
  for (int o = tid; o < 256; o += ENT) {
    const int oc = o >> 2, p = o & 3;
    c1[1024 + o] = b3[oc] + c1[p * 64 + oc] + c1[260 + p * 64 + oc] + c1[520 + p * 64 + oc];
  }
  __syncthreads();
  {
    const int d  = tid & 63;
    const int kc = tid >> 6;
    const int k0 = (kc * 256) / 3, k1 = ((kc + 1) * 256) / 3;
    float s = 0.0f;
    for (int k = k0; k < k1; ++k) s += ewT[k * 64 + d] * c1[1024 + k];
    c1[1536 + kc * 64 + d] = s;
  }
  __syncthreads();
  if (tid < 64) {
    z_all[(size_t)bid * 64 + tid] = eb[tid] + c1[1536 + tid] + c1[1600 + tid] + c1[1664 + tid];
  }
}

// ---------------------------------------------------------------------------
// z-Gram: z_gram[b][t][n] = z_t . z_n
// ---------------------------------------------------------------------------
__global__ __launch_bounds__(256) void gram_kernel(
    const float* __restrict__ z_all, float* __restrict__ z_gram)
{
  const int b = blockIdx.x;
  const int tid = threadIdx.x;
  __shared__ float zsb[64 * 65];
  for (int i = tid; i < 4096; i += 256) {
    const int tt = i >> 6, d = i & 63;
    zsb[tt * 65 + d] = z_all[((size_t)tt * 256 + b) * 64 + d];
  }
  __syncthreads();
  const int n = tid & 63, tg = tid >> 6;
  for (int tt = tg; tt < 64; tt += 4) {
    float s = 0.0f;
    #pragma unroll
    for (int d = 0; d < 64; ++d) s += zsb[tt * 65 + d] * zsb[n * 65 + d];
    z_gram[((size_t)b * 64 + tt) * 64 + n] = s;
  }
}

// ---------------------------------------------------------------------------
// gates partial GEMM: Gp[kc][256][2048] = XC[:,k0:k1] @ WT[k0:k1,:]
// grid (8jt*kcn, 16 bt) x 256 thr; thread = 4b x 4j.
// LDS stage TRANSPOSED xs[k][16b] -> inner loop: float4 W + float4 X + 16 FMA.
// blockIdx.x = jt*kcn+kc, gridDim.x multiple of 8 -> all btiles of one WT
// slice land on one XCD (L2-resident across steps).
// ---------------------------------------------------------------------------
__global__ __launch_bounds__(256) void gates_partial_kernel(
    const float* __restrict__ XC, const float* __restrict__ WT,
    float* __restrict__ Gp, const int kchunk, const int klog)
{
  extern __shared__ float xs[];          // [kchunk][16]
  const int bx  = blockIdx.x;
  const int kc  = bx & ((1 << klog) - 1);
  const int jt  = bx >> klog;
  const int tid = threadIdx.x;
  const int tj  = tid & 63, tb = tid >> 6;
  const int k0  = kc * kchunk;
  const int b0  = blockIdx.y * 16;
  const int j0  = jt * 256 + tj * 4;

  const int NS = 16 * kchunk;
  for (int i = tid; i < NS; i += 256) {
    const int k = i >> 4, b = i & 15;
    xs[k * 16 + b] = XC[(size_t)(b0 + b) * 580 + k0 + k];
  }
  __syncthreads();

  float acc[4][4];
  #pragma unroll
  for (int bb = 0; bb < 4; ++bb) { acc[bb][0]=0.f; acc[bb][1]=0.f; acc[bb][2]=0.f; acc[bb][3]=0.f; }

  const float* wp = WT + (size_t)k0 * 2048 + j0;
  const float* xp = xs + tb * 4;
  #pragma unroll 4
  for (int k = 0; k < kchunk; ++k) {
    const float4 w = *(const float4*)(wp + (size_t)k * 2048);
    const float4 x = *(const float4*)(xp + k * 16);
    const float xv[4] = {x.x, x.y, x.z, x.w};
    #pragma unroll
    for (int bb = 0; bb < 4; ++bb) {
      acc[bb][0] += xv[bb] * w.x; acc[bb][1] += xv[bb] * w.y;
      acc[bb][2] += xv[bb] * w.z; acc[bb][3] += xv[bb] * w.w;
    }
  }
  #pragma unroll
  for (int bb = 0; bb < 4; ++bb) {
    float4 r; r.x = acc[bb][0]; r.y = acc[bb][1]; r.z = acc[bb][2]; r.w = acc[bb][3];
    *(float4*)(Gp + ((size_t)kc * 256 + b0 + tb * 4 + bb) * 2048 + j0) = r;
  }
}

// ---------------------------------------------------------------------------
// fused step: LSTM elementwise from Gp -> h/C/XC-h, 69 dots, masked softmax
// from z_gram, memory read -> XC-kx. One block per batch element.
// ---------------------------------------------------------------------------
__global__ __launch_bounds__(256) void step_fused_kernel(
    const int t, const int kcn,
    const float* __restrict__ Gp, const float* __restrict__ bsum,
    float* __restrict__ C, const float* __restrict__ z_gram,
    float* __restrict__ MkT, float* __restrict__ XC, float* __restrict__ out,
    const float* __restrict__ out_w, const float* __restrict__ out_b,
    const float* __restrict__ gate_w, const float* __restrict__ gate_b,
    const float* __restrict__ key_w, const float* __restrict__ key_b,
    const float* __restrict__ conf_w, const float* __restrict__ conf_b)
{
  const int b   = blockIdx.x;
  const int tid = threadIdx.x;
  __shared__ __align__(16) float hs[512];
  __shared__ __align__(16) float wks[64];
  __shared__ __align__(16) float psum[256];
  __shared__ float sgv, kx64v;

  for (int jj = tid; jj < 512; jj += 256) {
    float gv[4];
    #pragma unroll
    for (int g = 0; g < 4; ++g) {
      float s = bsum[g * 512 + jj];
      for (int kc = 0; kc < kcn; ++kc)
        s += Gp[((size_t)kc * 256 + b) * 2048 + g * 512 + jj];
      gv[g] = s;
    }
    const size_t cidx = (size_t)b * 512 + jj;
    const float c2v = sigm(gv[1]) * C[cidx] + sigm(gv[0]) * tanhf(gv[2]);
    C[cidx] = c2v;
    const float h = sigm(gv[3]) * tanhf(c2v);
    hs[jj] = h;
    XC[(size_t)b * 580 + 65 + jj] = h;
  }
  __syncthreads();

  const int wv = tid >> 6, lane = tid & 63;
  for (int d = wv; d < 69; d += 4) {
    const float* row = (d < 64) ? (key_w + (size_t)d * 512)
                     : (d < 68) ? (out_w + (size_t)(d - 64) * 512)
                                : gate_w;
    float a = 0.0f;
    #pragma unroll
    for (int k = 0; k < 8; ++k) a += hs[lane + k * 64] * row[lane + k * 64];
    #pragma unroll
    for (int m = 32; m > 0; m >>= 1) a += __shfl_xor(a, m);
    if (lane == 0) {
      if (d < 64)      MkT[(size_t)b * 4096 + d * 64 + t] = a + key_b[d];
      else if (d < 68) out[(size_t)t * 1024 + b * 4 + (d - 64)] = a + out_b[d - 64];
      else             sgv = sigm(a + gate_b[0]);
    }
  }
  __syncthreads();

  if (t == 0) {
    if (tid < 65) XC[(size_t)b * 580 + tid] = 0.0f;
    return;
  }

  if (tid < 64) {
    const int n = tid;
    const float sim = z_gram[((size_t)b * 64 + t) * 64 + n];
    const bool valid = (n < t);
    float mx = valid ? sim : -3.0e38f;
    #pragma unroll
    for (int m = 32; m > 0; m >>= 1) mx = fmaxf(mx, __shfl_xor(mx, m));
    const float p = valid ? expf(sim - mx) : 0.0f;
    float sum = p;
    #pragma unroll
    for (int m = 32; m > 0; m >>= 1) sum += __shfl_xor(sum, m);
    const float wk = p / sum;
    wks[n] = wk;
    float kcv = wk * sigm(sim * conf_w[0] + conf_b[0]);
    #pragma unroll
    for (int m = 32; m > 0; m >>= 1) kcv += __shfl_xor(kcv, m);
    if (n == 0) kx64v = kcv;
  }
  __syncthreads();

  {
    const int d = tid >> 2, q = tid & 3;
    const float* mr = MkT + (size_t)b * 4096 + d * 64 + q * 16;
    const float* wr = wks + q * 16;
    float a = 0.0f;
    #pragma unroll
    for (int i = 0; i < 4; ++i) {
      const float4 m4 = *(const float4*)(mr + 4 * i);
      const float4 w4 = *(const float4*)(wr + 4 * i);
      a += m4.x * w4.x + m4.y * w4.y + m4.z * w4.z + m4.w * w4.w;
    }
    psum[tid] = a;
  }
  __syncthreads();
  if (tid < 64) {
    XC[(size_t)b * 580 + tid] = sgv * (psum[tid * 4] + psum[tid * 4 + 1] + psum[tid * 4 + 2] + psum[tid * 4 + 3]);
  } else if (tid == 64) {
    XC[(size_t)b * 580 + 64] = sgv * kx64v;
  }
}

// ---------------------------------------------------------------------------
extern "C" void kernel_launch(void* const* d_in, const int* in_sizes, int n_in,
                              void* d_out, int out_size, void* d_ws, size_t ws_size,
                              hipStream_t stream) {
  const float* images = (const float*)d_in[0];
  const float* w1     = (const float*)d_in[1];
  const float* b1     = (const float*)d_in[2];
  const float* w2     = (const float*)d_in[3];
  const float* b2     = (const float*)d_in[4];
  const float* w3     = (const float*)d_in[5];
  const float* b3     = (const float*)d_in[6];
  const float* ew     = (const float*)d_in[7];
  const float* eb     = (const float*)d_in[8];
  const float* w_ih   = (const float*)d_in[9];
  const float* w_hh   = (const float*)d_in[10];
  const float* b_ih   = (const float*)d_in[11];
  const float* b_hh   = (const float*)d_in[12];
  const float* out_w  = (const float*)d_in[13];
  const float* out_b  = (const float*)d_in[14];
  const float* gate_w = (const float*)d_in[15];
  const float* gate_b = (const float*)d_in[16];
  const float* key_w  = (const float*)d_in[17];
  const float* key_b  = (const float*)d_in[18];
  const float* conf_w = (const float*)d_in[19];
  const float* conf_b = (const float*)d_in[20];
  float* out = (float*)d_out;
  float* ws  = (float*)d_ws;

  // ws layout (floats)
  float* WT     = ws;                  // 1,187,840
  float* bsum   = ws + 1187840;        // 2,048
  float* w1T    = ws + 1189888;        // 1,536
  float* w2T    = ws + 1191424;        // 32,768
  float* w3T    = ws + 1224192;        // 65,536
  float* ewT    = ws + 1289728;        // 16,384
  float* z_all  = ws + 1306112;        // 1,048,576
  float* MkT    = ws + 2354688;        // 1,048,576
  float* C      = ws + 3403264;        // 131,072
  float* XC     = ws + 3534336;        // 148,480
  float* z_gram = ws + 3682816;        // 1,048,576
  float* Gp     = ws + 4731392;        // kcn * 524,288

  int kcn = 4, klog = 2, kchunk = 145;
  if (ws_size < (4731392ull + 4ull * 524288ull) * 4ull) { kcn = 2; klog = 1; kchunk = 290; }
  if (ws_size < (4731392ull + 2ull * 524288ull) * 4ull) { kcn = 1; klog = 0; kchunk = 580; }

  const size_t baseF  = 4731392ull + (size_t)kcn * 524288ull;
  float* c1g          = ws + baseF;
  const size_t availF = (ws_size / 4 > baseF) ? (ws_size / 4 - baseF) : 0;
  long chunkL = (long)(availF / 7680ull);
  int chunk = (chunkL > 16384) ? 16384 : (int)chunkL;

  hipMemsetAsync(C,  0, 131072 * sizeof(float), stream);
  hipMemsetAsync(XC, 0, 148480 * sizeof(float), stream);

  prep_kernel<<<(PREP_N + 255) / 256, 256, 0, stream>>>(
      w_ih, w_hh, b_ih, b_hh, w1, w2, w3, ew, WT, bsum, w1T, w2T, w3T, ewT);

  if (chunk >= 2048) {
    for (int s0 = 0; s0 < 16384; s0 += chunk) {
      const int n = (16384 - s0 < chunk) ? (16384 - s0) : chunk;
      conv1_kernel<<<n, ENT, 0, stream>>>(images, w1T, b1, c1g, s0);
      enc2_kernel<<<n, ENT, 0, stream>>>(c1g, w2T, b2, w3T, b3, ewT, eb, z_all, s0);
    }
  } else {
    encoder_kernel<<<16384, ENT, 0, stream>>>(images, w1T, b1, w2T, b2, w3T, b3, ewT, eb, z_all);
  }

  gram_kernel<<<256, 256, 0, stream>>>(z_all, z_gram);

  const size_t lds_stage = (size_t)16 * kchunk * sizeof(float);
  for (int t = 0; t < 64; ++t) {
    gates_partial_kernel<<<dim3(8 * kcn, 16), 256, lds_stage, stream>>>(
        XC, WT, Gp, kchunk, klog);
    step_fused_kernel<<<256, 256, 0, stream>>>(
        t, kcn, Gp, bsum, C, z_gram, MkT, XC, out,
        out_w, out_b, gate_w, gate_b, key_w, key_b, conf_w, conf_b);
  }
}